// Round 1
// baseline (17.264 us; speedup 1.0000x reference)
//
#include <hip/hip_runtime.h>

// FeatureViewEncoder: per-feature Conv1d(1,H,3) + mask + max-over-time.
// Shapes: input_visit [B=128, V=200, F=64] f32, visit_mask [B,1,L=198] i32,
// conv_w [F,H=128,K=3] f32, conv_b [F,H] f32, out [B,F,H] f32.
// out[b,f,h] = max_{l valid} ( sum_k x[b,l+k,f]*w[f,h,k] + bias[f,h] ), else -1e9.

#define NEG_INF_F (-1e9f)

constexpr int B_ = 128;
constexpr int V_ = 200;
constexpr int F_ = 64;
constexpr int H_ = 128;
constexpr int K_ = 3;
constexpr int L_ = V_ - K_ + 1;  // 198

constexpr int FG = 8;        // features per block
constexpr int NTHR = 256;    // threads per block
constexpr int HPT = 4;       // h-outputs per thread (128 h / 32 threads-per-f)

__global__ __launch_bounds__(NTHR)
void fve_kernel(const float* __restrict__ x,     // [B,V,F]
                const int*   __restrict__ mask,  // [B,1,L]
                const float* __restrict__ w,     // [F,H,K]
                const float* __restrict__ bias,  // [F,H]
                float* __restrict__ out)         // [B,F,H]
{
    __shared__ float xs[FG][V_ + 1];  // +1 pad (write-side conflict hygiene)
    __shared__ int   vlist[L_];
    __shared__ int   vcnt;

    const int b  = blockIdx.x >> 3;   // grid = B * (F/FG) = 1024
    const int fg = blockIdx.x & 7;
    const int f0 = fg * FG;
    const int t  = threadIdx.x;

    if (t == 0) vcnt = 0;
    __syncthreads();

    // Stage x[b, :, f0:f0+8] -> LDS, transposed to xs[f_local][v].
    // 400 float4 loads (two 16B halves per v), coalesced 32B per v.
    for (int idx = t; idx < V_ * 2; idx += NTHR) {
        const int v = idx >> 1, half = idx & 1;
        const float4 vec = *reinterpret_cast<const float4*>(
            x + ((size_t)b * V_ + v) * F_ + f0 + half * 4);
        const int fl = half * 4;
        xs[fl + 0][v] = vec.x;
        xs[fl + 1][v] = vec.y;
        xs[fl + 2][v] = vec.z;
        xs[fl + 3][v] = vec.w;
    }

    // Compact valid time-steps (order irrelevant for max).
    for (int l = t; l < L_; l += NTHR) {
        if (mask[b * L_ + l] != 0) {
            const int p = atomicAdd(&vcnt, 1);
            vlist[p] = l;
        }
    }
    __syncthreads();

    const int f_local = t >> 5;            // 0..7
    const int f       = f0 + f_local;
    const int h0      = (t & 31) * HPT;    // 0,4,...,124

    // 12 contiguous weight floats for h0..h0+3 (layout [F,H,K]).
    const float* wp = w + ((size_t)f * H_ + h0) * K_;
    const float4 w0 = *reinterpret_cast<const float4*>(wp);
    const float4 w1 = *reinterpret_cast<const float4*>(wp + 4);
    const float4 w2 = *reinterpret_cast<const float4*>(wp + 8);
    const float4 bb = *reinterpret_cast<const float4*>(bias + (size_t)f * H_ + h0);

    float m0 = NEG_INF_F, m1 = NEG_INF_F, m2 = NEG_INF_F, m3 = NEG_INF_F;
    const int n = vcnt;
    for (int i = 0; i < n; ++i) {
        const int l = vlist[i];                 // uniform -> LDS broadcast
        const float x0 = xs[f_local][l];
        const float x1 = xs[f_local][l + 1];
        const float x2 = xs[f_local][l + 2];
        // per-h kernel taps: h+0:(w0.x,w0.y,w0.z) h+1:(w0.w,w1.x,w1.y)
        //                    h+2:(w1.z,w1.w,w2.x) h+3:(w2.y,w2.z,w2.w)
        const float c0 = fmaf(x0, w0.x, fmaf(x1, w0.y, fmaf(x2, w0.z, bb.x)));
        const float c1 = fmaf(x0, w0.w, fmaf(x1, w1.x, fmaf(x2, w1.y, bb.y)));
        const float c2 = fmaf(x0, w1.z, fmaf(x1, w1.w, fmaf(x2, w2.x, bb.z)));
        const float c3 = fmaf(x0, w2.y, fmaf(x1, w2.z, fmaf(x2, w2.w, bb.w)));
        m0 = fmaxf(m0, c0);
        m1 = fmaxf(m1, c1);
        m2 = fmaxf(m2, c2);
        m3 = fmaxf(m3, c3);
    }

    *reinterpret_cast<float4*>(out + ((size_t)b * F_ + f) * H_ + h0) =
        make_float4(m0, m1, m2, m3);
}

extern "C" void kernel_launch(void* const* d_in, const int* in_sizes, int n_in,
                              void* d_out, int out_size, void* d_ws, size_t ws_size,
                              hipStream_t stream) {
    const float* x    = (const float*)d_in[0];  // input_visit
    const int*   mask = (const int*)d_in[1];    // visit_mask
    const float* w    = (const float*)d_in[2];  // conv_w
    const float* bias = (const float*)d_in[3];  // conv_b
    float* out = (float*)d_out;

    const int grid = B_ * (F_ / FG);  // 1024
    fve_kernel<<<grid, NTHR, 0, stream>>>(x, mask, w, bias, out);
}